// Round 1
// baseline (509.559 us; speedup 1.0000x reference)
//
#include <hip/hip_runtime.h>

#define NV   2048
#define NV4  (NV / 4)

__device__ __forceinline__ float fast_rcp(float x) {
    float r = __builtin_amdgcn_rcpf(x);
    // one Newton-Raphson refinement: r' = r + r*(1 - x*r)
    r = fmaf(r, fmaf(-x, r, 1.0f), r);
    return r;
}

__device__ __forceinline__ void fwd4(const float4& av, const float4& bv,
                                     const float4& cv, const float4& dv,
                                     float& lcp, float& ldp,
                                     float4& cpv, float4& dpv) {
    float den, r;
    den = bv.x - av.x * lcp;  r = fast_rcp(den);
    cpv.x = cv.x * r;         dpv.x = (dv.x - av.x * ldp) * r;
    den = bv.y - av.y * cpv.x; r = fast_rcp(den);
    cpv.y = cv.y * r;         dpv.y = (dv.y - av.y * dpv.x) * r;
    den = bv.z - av.z * cpv.y; r = fast_rcp(den);
    cpv.z = cv.z * r;         dpv.z = (dv.z - av.z * dpv.y) * r;
    den = bv.w - av.w * cpv.z; r = fast_rcp(den);
    cpv.w = cv.w * r;         dpv.w = (dv.w - av.w * dpv.z) * r;
    lcp = cpv.w; ldp = dpv.w;
}

extern "C" __global__ void __launch_bounds__(64, 1)
thomas_kernel(const float* __restrict__ a, const float* __restrict__ b,
              const float* __restrict__ c, const float* __restrict__ d,
              float* __restrict__ cp_ws, float* __restrict__ out, int nx)
{
    int sys = blockIdx.x * 64 + threadIdx.x;
    if (sys >= nx) return;

    const float4* a4 = reinterpret_cast<const float4*>(a) + (size_t)sys * NV4;
    const float4* b4 = reinterpret_cast<const float4*>(b) + (size_t)sys * NV4;
    const float4* c4 = reinterpret_cast<const float4*>(c) + (size_t)sys * NV4;
    const float4* d4 = reinterpret_cast<const float4*>(d) + (size_t)sys * NV4;
    float4* cp4 = reinterpret_cast<float4*>(cp_ws) + (size_t)sys * NV4;
    float4* o4  = reinterpret_cast<float4*>(out)   + (size_t)sys * NV4;

    // ---------------- forward sweep: cp -> ws, dp -> out ----------------
    float lcp = 0.0f, ldp = 0.0f;
    float4 av = a4[0], bv = b4[0], cv = c4[0], dv = d4[0];

    #pragma unroll 2
    for (int j = 0; j < NV4 - 1; ++j) {
        // prefetch next iteration before the serial dependency chain
        float4 an = a4[j + 1];
        float4 bn = b4[j + 1];
        float4 cn = c4[j + 1];
        float4 dn = d4[j + 1];

        float4 cpv, dpv;
        fwd4(av, bv, cv, dv, lcp, ldp, cpv, dpv);
        cp4[j] = cpv;
        o4[j]  = dpv;

        av = an; bv = bn; cv = cn; dv = dn;
    }
    {
        float4 cpv, dpv;
        fwd4(av, bv, cv, dv, lcp, ldp, cpv, dpv);
        cp4[NV4 - 1] = cpv;
        o4[NV4 - 1]  = dpv;
    }

    // ---------------- backward sweep: in-place on out ----------------
    float x = 0.0f;
    float4 cpv = cp4[NV4 - 1];
    float4 dpv = o4[NV4 - 1];

    #pragma unroll 2
    for (int j = NV4 - 1; j > 0; --j) {
        float4 cpn = cp4[j - 1];
        float4 dpn = o4[j - 1];

        float4 xv;
        xv.w = dpv.w - cpv.w * x;
        xv.z = dpv.z - cpv.z * xv.w;
        xv.y = dpv.y - cpv.y * xv.z;
        xv.x = dpv.x - cpv.x * xv.y;
        o4[j] = xv;
        x = xv.x;

        cpv = cpn; dpv = dpn;
    }
    {
        float4 xv;
        xv.w = dpv.w - cpv.w * x;
        xv.z = dpv.z - cpv.z * xv.w;
        xv.y = dpv.y - cpv.y * xv.z;
        xv.x = dpv.x - cpv.x * xv.y;
        o4[0] = xv;
    }
}

extern "C" void kernel_launch(void* const* d_in, const int* in_sizes, int n_in,
                              void* d_out, int out_size, void* d_ws, size_t ws_size,
                              hipStream_t stream) {
    const float* a = (const float*)d_in[0];
    const float* b = (const float*)d_in[1];
    const float* c = (const float*)d_in[2];
    const float* d = (const float*)d_in[3];
    float* out   = (float*)d_out;
    float* cp_ws = (float*)d_ws;   // NX*NV*4 = 64 MiB of scratch for cp

    int nx = in_sizes[0] / NV;
    int block = 64;
    int grid  = (nx + block - 1) / block;
    hipLaunchKernelGGL(thomas_kernel, dim3(grid), dim3(block), 0, stream,
                       a, b, c, d, cp_ws, out, nx);
}

// Round 2
// 339.376 us; speedup vs baseline: 1.5015x; 1.5015x over previous
//
#include <hip/hip_runtime.h>

#define NV 2048
#define L  32          // chunk length per thread
#define W  8           // warm-up overlap (error ~0.22^8 ~ 5e-6)
#define C  (NV / L)    // 64 chunks per system

__device__ __forceinline__ float fast_rcp(float x) {
    float r = __builtin_amdgcn_rcpf(x);
    r = fmaf(r, fmaf(-x, r, 1.0f), r);   // one NR step
    return r;
}

__device__ __forceinline__ void fstep(float aa, float bb, float cc, float dd,
                                      float& lcp, float& ldp) {
    float den = fmaf(-aa, lcp, bb);      // b - a*cp_prev
    float r   = fast_rcp(den);
    lcp = cc * r;                        // cp = c/den
    ldp = fmaf(-aa, ldp, dd) * r;        // dp = (d - a*dp_prev)/den
}

extern "C" __global__ void __launch_bounds__(256)
thomas_ov(const float* __restrict__ a, const float* __restrict__ b,
          const float* __restrict__ c, const float* __restrict__ d,
          float* __restrict__ out, int nx)
{
    int t   = blockIdx.x * 256 + threadIdx.x;
    int sys = t >> 6;            // t / C
    int ch  = t & (C - 1);       // t % C
    if (sys >= nx) return;

    size_t g0 = (size_t)sys * NV + (size_t)ch * L;

    const float4* a4 = reinterpret_cast<const float4*>(a + g0);
    const float4* b4 = reinterpret_cast<const float4*>(b + g0);
    const float4* c4 = reinterpret_cast<const float4*>(c + g0);
    const float4* d4 = reinterpret_cast<const float4*>(d + g0);
    float4* o4 = reinterpret_cast<float4*>(out + g0);

    float cp[L + W], dp[L + W];
    float lcp = 0.0f, ldp = 0.0f;

    // ---- forward warm-up: rel indices [-W, 0), only if a previous chunk exists
    if (ch > 0) {
        #pragma unroll
        for (int q = -(W / 4); q < 0; ++q) {
            float4 av = a4[q], bv = b4[q], cv = c4[q], dv = d4[q];
            fstep(av.x, bv.x, cv.x, dv.x, lcp, ldp);
            fstep(av.y, bv.y, cv.y, dv.y, lcp, ldp);
            fstep(av.z, bv.z, cv.z, dv.z, lcp, ldp);
            fstep(av.w, bv.w, cv.w, dv.w, lcp, ldp);
        }
    }

    // ---- main forward sweep: rel [0, L), store cp/dp in registers
    #pragma unroll
    for (int q = 0; q < L / 4; ++q) {
        float4 av = a4[q], bv = b4[q], cv = c4[q], dv = d4[q];
        fstep(av.x, bv.x, cv.x, dv.x, lcp, ldp); cp[4*q+0] = lcp; dp[4*q+0] = ldp;
        fstep(av.y, bv.y, cv.y, dv.y, lcp, ldp); cp[4*q+1] = lcp; dp[4*q+1] = ldp;
        fstep(av.z, bv.z, cv.z, dv.z, lcp, ldp); cp[4*q+2] = lcp; dp[4*q+2] = ldp;
        fstep(av.w, bv.w, cv.w, dv.w, lcp, ldp); cp[4*q+3] = lcp; dp[4*q+3] = ldp;
    }

    float x = 0.0f;
    // ---- forward extension + backward warm-up: rel [L, L+W), only if a next chunk exists
    if (ch < C - 1) {
        #pragma unroll
        for (int q = L / 4; q < (L + W) / 4; ++q) {
            float4 av = a4[q], bv = b4[q], cv = c4[q], dv = d4[q];
            fstep(av.x, bv.x, cv.x, dv.x, lcp, ldp); cp[4*q+0] = lcp; dp[4*q+0] = ldp;
            fstep(av.y, bv.y, cv.y, dv.y, lcp, ldp); cp[4*q+1] = lcp; dp[4*q+1] = ldp;
            fstep(av.z, bv.z, cv.z, dv.z, lcp, ldp); cp[4*q+2] = lcp; dp[4*q+2] = ldp;
            fstep(av.w, bv.w, cv.w, dv.w, lcp, ldp); cp[4*q+3] = lcp; dp[4*q+3] = ldp;
        }
        #pragma unroll
        for (int k = L + W - 1; k >= L; --k)
            x = fmaf(-cp[k], x, dp[k]);   // backward warm-up (discarded region)
    }
    // else: last chunk — x starts at exactly 0, matching the reference

    // ---- back-substitution over own chunk, write out in float4 groups
    #pragma unroll
    for (int q = L / 4 - 1; q >= 0; --q) {
        float4 xv;
        xv.w = fmaf(-cp[4*q+3], x,    dp[4*q+3]);
        xv.z = fmaf(-cp[4*q+2], xv.w, dp[4*q+2]);
        xv.y = fmaf(-cp[4*q+1], xv.z, dp[4*q+1]);
        xv.x = fmaf(-cp[4*q+0], xv.y, dp[4*q+0]);
        x = xv.x;
        o4[q] = xv;
    }
}

extern "C" void kernel_launch(void* const* d_in, const int* in_sizes, int n_in,
                              void* d_out, int out_size, void* d_ws, size_t ws_size,
                              hipStream_t stream) {
    const float* a = (const float*)d_in[0];
    const float* b = (const float*)d_in[1];
    const float* c = (const float*)d_in[2];
    const float* d = (const float*)d_in[3];
    float* out = (float*)d_out;

    int nx = in_sizes[0] / NV;
    int total = nx * C;
    int block = 256;
    int grid  = (total + block - 1) / block;
    hipLaunchKernelGGL(thomas_ov, dim3(grid), dim3(block), 0, stream,
                       a, b, c, d, out, nx);
}

// Round 5
// 254.422 us; speedup vs baseline: 2.0028x; 1.3339x over previous
//
#include <hip/hip_runtime.h>

#define NV    2048
#define HALF  1024
#define W     8            // warm-up halo each side (err ~0.22^8 ~ 5e-6)
#define LPT   8            // floats per lane (main chunk)
#define TPB   128          // threads per block = HALF / LPT
#define SLOTS 260          // float4 slots per staged array: (HALF + 2W)/4

__device__ __forceinline__ float fast_rcp(float x) {
    float r = __builtin_amdgcn_rcpf(x);
    r = fmaf(r, fmaf(-x, r, 1.0f), r);   // one NR step
    return r;
}

__device__ __forceinline__ void fstep(float aa, float bb, float cc, float dd,
                                      float& lcp, float& ldp) {
    float den = fmaf(-aa, lcp, bb);      // b - a*cp_prev
    float r   = fast_rcp(den);
    lcp = cc * r;                        // cp = c/den
    ldp = fmaf(-aa, ldp, dd) * r;        // dp = (d - a*dp_prev)/den
}

// involution swizzle on float4 slot index: XORs bits0-1 with bits3-4.
// identity on slots 256..259 (tail). Spreads lane-strided reads over all
// 8 bank-groups -> conflict-free ds_read_b128.
__device__ __forceinline__ int swz(int w) { return w ^ ((w >> 3) & 3); }

__device__ __forceinline__ void gload16(const float* gsrc, float4* ldst) {
    __builtin_amdgcn_global_load_lds(
        (const __attribute__((address_space(1))) void*)gsrc,
        (__attribute__((address_space(3))) void*)ldst, 16, 0, 0);
}

extern "C" __global__ void __launch_bounds__(TPB)
thomas_lds(const float* __restrict__ a, const float* __restrict__ b,
           const float* __restrict__ c, const float* __restrict__ d,
           float* __restrict__ out, int nx, long total)
{
    __shared__ float4 lbuf[4 * SLOTS];

    const int tid = threadIdx.x;
    const int sys = blockIdx.x >> 1;
    const int h   = blockIdx.x & 1;

    const long start  = (long)sys * NV + (long)h * HALF;
    const long base_f = start - W;         // float index of buffer origin
    const float* arrs[4] = { a, b, c, d };

    // ---- coalesced staging: global -> LDS, swizzle applied on SOURCE addr ----
    // slot s holds global float4 (base_f/4 + swz(s)); reader of data w looks
    // at slot swz(w). swz permutes only within 64-slot segments -> the wave's
    // 64 global addresses are a permutation of 1KB contiguous = coalesced.
    #pragma unroll
    for (int arr = 0; arr < 4; ++arr) {
        const float* gp = arrs[arr];
        #pragma unroll
        for (int r = 0; r < 2; ++r) {
            int s = r * TPB + tid;                       // slot this thread fills
            int w = swz(s);
            long g = base_f + 4L * w;
            g = (g < 0) ? 0 : (g > total - 4 ? total - 4 : g);
            // LDS dest must be wave-uniform base (+ lane*16 applied by HW)
            gload16(gp + g, &lbuf[arr * SLOTS + r * TPB + (tid & ~63)]);
        }
        if (tid < SLOTS - 256) {                         // tail slots 256..259
            int s = 256 + tid;                           // swz = identity here
            long g = base_f + 4L * s;
            g = (g < 0) ? 0 : (g > total - 4 ? total - 4 : g);
            gload16(gp + g, &lbuf[arr * SLOTS + 256]);
        }
    }
    __syncthreads();   // drains vmcnt (global_load_lds) before LDS reads

    // ---- per-lane chunk solve from LDS --------------------------------------
    // lane's buffer layout (float4 slots, w0 = 2*tid):
    //   slots w0+0..1 : warm-up   = global [start + 8*tid - 8, start + 8*tid)
    //   slots w0+2..3 : main      = global [start + 8*tid,     start + 8*tid + 8)
    //   slots w0+4..5 : extension = global [start + 8*tid + 8, start + 8*tid + 16)
    const int chg = h * TPB + tid;            // chunk id within system, [0,256)
    const bool pre  = (chg > 0);
    const bool post = (chg < NV / LPT - 1);
    const int  w0   = 2 * tid;

    float cpm[LPT], dpm[LPT];
    float cpe[W],  dpe[W];
    float lcp = 0.0f, ldp = 0.0f;

    #define RD(arr, q) lbuf[(arr) * SLOTS + swz(w0 + (q))]

    if (pre) {   // forward warm-up from cp=dp=0 (exact for chg==0 -> skipped)
        #pragma unroll
        for (int q = 0; q < 2; ++q) {
            float4 av = RD(0, q), bv = RD(1, q), cv = RD(2, q), dv = RD(3, q);
            fstep(av.x, bv.x, cv.x, dv.x, lcp, ldp);
            fstep(av.y, bv.y, cv.y, dv.y, lcp, ldp);
            fstep(av.z, bv.z, cv.z, dv.z, lcp, ldp);
            fstep(av.w, bv.w, cv.w, dv.w, lcp, ldp);
        }
    }
    #pragma unroll
    for (int q = 2; q < 4; ++q) {   // main chunk: store cp/dp in registers
        float4 av = RD(0, q), bv = RD(1, q), cv = RD(2, q), dv = RD(3, q);
        int m = 4 * (q - 2);
        fstep(av.x, bv.x, cv.x, dv.x, lcp, ldp); cpm[m+0] = lcp; dpm[m+0] = ldp;
        fstep(av.y, bv.y, cv.y, dv.y, lcp, ldp); cpm[m+1] = lcp; dpm[m+1] = ldp;
        fstep(av.z, bv.z, cv.z, dv.z, lcp, ldp); cpm[m+2] = lcp; dpm[m+2] = ldp;
        fstep(av.w, bv.w, cv.w, dv.w, lcp, ldp); cpm[m+3] = lcp; dpm[m+3] = ldp;
    }
    float x = 0.0f;
    if (post) {  // forward extension + backward warm-up from x=0
        #pragma unroll
        for (int q = 4; q < 6; ++q) {
            float4 av = RD(0, q), bv = RD(1, q), cv = RD(2, q), dv = RD(3, q);
            int m = 4 * (q - 4);
            fstep(av.x, bv.x, cv.x, dv.x, lcp, ldp); cpe[m+0] = lcp; dpe[m+0] = ldp;
            fstep(av.y, bv.y, cv.y, dv.y, lcp, ldp); cpe[m+1] = lcp; dpe[m+1] = ldp;
            fstep(av.z, bv.z, cv.z, dv.z, lcp, ldp); cpe[m+2] = lcp; dpe[m+2] = ldp;
            fstep(av.w, bv.w, cv.w, dv.w, lcp, ldp); cpe[m+3] = lcp; dpe[m+3] = ldp;
        }
        #pragma unroll
        for (int k = W - 1; k >= 0; --k)
            x = fmaf(-cpe[k], x, dpe[k]);
    }
    // else: last chunk — x starts at exactly 0, matching the reference
    #undef RD

    // ---- back-substitution over own chunk + vectorized store ----------------
    float4* og = reinterpret_cast<float4*>(out + start) + 2 * tid;
    #pragma unroll
    for (int q = 1; q >= 0; --q) {
        float4 xv;
        xv.w = fmaf(-cpm[4*q+3], x,    dpm[4*q+3]);
        xv.z = fmaf(-cpm[4*q+2], xv.w, dpm[4*q+2]);
        xv.y = fmaf(-cpm[4*q+1], xv.z, dpm[4*q+1]);
        xv.x = fmaf(-cpm[4*q+0], xv.y, dpm[4*q+0]);
        x = xv.x;
        og[q] = xv;
    }
}

extern "C" void kernel_launch(void* const* d_in, const int* in_sizes, int n_in,
                              void* d_out, int out_size, void* d_ws, size_t ws_size,
                              hipStream_t stream) {
    const float* a = (const float*)d_in[0];
    const float* b = (const float*)d_in[1];
    const float* c = (const float*)d_in[2];
    const float* d = (const float*)d_in[3];
    float* out = (float*)d_out;

    int nx = in_sizes[0] / NV;
    long total = (long)in_sizes[0];
    int grid = nx * 2;   // one block per half-system
    hipLaunchKernelGGL(thomas_lds, dim3(grid), dim3(TPB), 0, stream,
                       a, b, c, d, out, nx, total);
}